// Round 1
// baseline (705.702 us; speedup 1.0000x reference)
//
#include <hip/hip_runtime.h>

#define NSEG 40000
#define NREG 1000
#define NEDGE 640000
#define HID 256
#define KCAT 1280   // 5 * HID

typedef float f32x4 __attribute__((ext_vector_type(4)));
typedef short s16x8 __attribute__((ext_vector_type(8)));
typedef unsigned short u16x4 __attribute__((ext_vector_type(4)));
typedef unsigned short u16x8 __attribute__((ext_vector_type(8)));

__device__ __forceinline__ unsigned short f2bf(float f) {
    unsigned u = __builtin_bit_cast(unsigned, f);
    u += 0x7FFFu + ((u >> 16) & 1u);   // round-to-nearest-even
    return (unsigned short)(u >> 16);
}
__device__ __forceinline__ float bf2f(unsigned short h) {
    unsigned u = ((unsigned)h) << 16;
    return __builtin_bit_cast(float, u);
}

// ---------------------------------------------------------------- edge dtype
// edge_index is jnp.int64 in the reference, but with JAX x64 disabled it is
// materialized as int32. Detect at runtime: values are in [0,40000), so for
// int64 storage every odd 32-bit word (high half) is 0.
__global__ void detect_kernel(const unsigned int* __restrict__ E, int* flag) {
    int lane = threadIdx.x;
    unsigned v = E[2 * lane + 1];
    unsigned long long m = __ballot(v == 0u);
    if (lane == 0) *flag = (__popcll(m) >= 48) ? 1 : 0;
}

__device__ __forceinline__ int edge_at(const void* E, int idx, int is64) {
    return is64 ? (int)((const long long*)E)[idx] : ((const int*)E)[idx];
}

// ---------------------------------------------------------------- CSR build
__global__ __launch_bounds__(256) void deg_cnt_kernel(const void* __restrict__ E,
                                                      const int* __restrict__ flag,
                                                      int* deg, int* cnt) {
    int e = blockIdx.x * 256 + threadIdx.x;
    if (e >= NEDGE) return;
    int is64 = *flag;
    int s = edge_at(E, e, is64);
    int d = edge_at(E, e + NEDGE, is64);
    if (s != d) {
        atomicAdd(&deg[s], 1);
        atomicAdd(&cnt[d], 1);
    }
}

__global__ __launch_bounds__(256) void dinv_kernel(const int* __restrict__ deg,
                                                   float* __restrict__ dinv) {
    int i = blockIdx.x * 256 + threadIdx.x;
    if (i < NSEG) {
        int d = deg[i];
        dinv[i] = d > 0 ? rsqrtf((float)d) : 0.f;
    }
}

__global__ __launch_bounds__(1024) void scan_kernel(const int* __restrict__ cnt,
                                                    int* __restrict__ rowptr,
                                                    int* __restrict__ cursor) {
    __shared__ int ps[1024];
    const int t = threadIdx.x;
    const int CH = 40;  // 1024*40 >= 40000
    int base = t * CH;
    int s = 0;
    for (int i = 0; i < CH; ++i) {
        int idx = base + i;
        if (idx < NSEG) s += cnt[idx];
    }
    ps[t] = s;
    __syncthreads();
    for (int off = 1; off < 1024; off <<= 1) {
        int v = 0;
        if (t >= off) v = ps[t - off];
        __syncthreads();
        if (t >= off) ps[t] += v;
        __syncthreads();
    }
    int run = (t == 0) ? 0 : ps[t - 1];
    for (int i = 0; i < CH; ++i) {
        int idx = base + i;
        if (idx < NSEG) {
            rowptr[idx] = run;
            cursor[idx] = run;
            run += cnt[idx];
        }
    }
    if (t == 1023) rowptr[NSEG] = ps[1023];
}

__global__ __launch_bounds__(256) void scatter_kernel(const void* __restrict__ E,
                                                      const int* __restrict__ flag,
                                                      const float* __restrict__ dinv,
                                                      int* cursor,
                                                      int* __restrict__ colidx,
                                                      float* __restrict__ val) {
    int e = blockIdx.x * 256 + threadIdx.x;
    if (e >= NEDGE) return;
    int is64 = *flag;
    int s = edge_at(E, e, is64);
    int d = edge_at(E, e + NEDGE, is64);
    if (s != d) {
        int pos = atomicAdd(&cursor[d], 1);
        colidx[pos] = s;
        val[pos] = -dinv[s] * dinv[d];
    }
}

// ---------------------------------------------------------------- weight prep
// Pt[n][k] = bf16(P[k][n]);  Wt[n][k] = bf16(W[k][n])  (k-major for MFMA frags)
__global__ void prep_pt_kernel(const float* __restrict__ P, unsigned short* __restrict__ Pt) {
    int n = blockIdx.x;
    for (int k = threadIdx.x; k < NREG; k += blockDim.x)
        Pt[(size_t)n * NREG + k] = f2bf(P[(size_t)k * HID + n]);
}
__global__ void prep_wt_kernel(const float* __restrict__ W, unsigned short* __restrict__ Wt) {
    int n = blockIdx.x;
    for (int k = threadIdx.x; k < KCAT; k += blockDim.x)
        Wt[(size_t)n * KCAT + k] = f2bf(W[(size_t)k * HID + n]);
}

// ---------------------------------------------------------------- GEMM1
// raw = S @ P  (fp32 out to d_out[seg_low_raw]) ; also bf16 copy into Xcat seg 0.
// BM=64 BN=64 BK=32, 256 thr = 4 waves (2x2), wave tile 32x32 (2x2 16x16x32 frags).
__global__ __launch_bounds__(256) void gemm1_kernel(const float* __restrict__ S,
                                                    const unsigned short* __restrict__ Pt,
                                                    float* __restrict__ raw,
                                                    unsigned short* __restrict__ xcat) {
    __shared__ unsigned short As[64][32];
    __shared__ unsigned short Bs[64][32];
    const int m0 = blockIdx.x * 64;
    const int n0 = blockIdx.y * 64;
    const int tid = threadIdx.x;
    const int lane = tid & 63, wid = tid >> 6;
    const int wm = wid >> 1, wn = wid & 1;
    const int r = lane & 15, q = lane >> 4;
    const int srow = tid >> 2, scol = (tid & 3) * 8;

    f32x4 acc00 = {0.f, 0.f, 0.f, 0.f};
    f32x4 acc01 = acc00, acc10 = acc00, acc11 = acc00;

    for (int kb = 0; kb < NREG; kb += 32) {
        const bool kvalid = (kb + scol + 8 <= NREG);  // NREG % 8 == 0: chunks all-or-nothing
        u16x8 av = {0, 0, 0, 0, 0, 0, 0, 0};
        u16x8 bv = {0, 0, 0, 0, 0, 0, 0, 0};
        if (kvalid) {
            const float* sp = S + (size_t)(m0 + srow) * NREG + kb + scol;
            f32x4 f0 = *(const f32x4*)sp;
            f32x4 f1 = *(const f32x4*)(sp + 4);
            av[0] = f2bf(f0[0]); av[1] = f2bf(f0[1]); av[2] = f2bf(f0[2]); av[3] = f2bf(f0[3]);
            av[4] = f2bf(f1[0]); av[5] = f2bf(f1[1]); av[6] = f2bf(f1[2]); av[7] = f2bf(f1[3]);
            bv = *(const u16x8*)(Pt + (size_t)(n0 + srow) * NREG + kb + scol);
        }
        __syncthreads();
        *(u16x8*)&As[srow][scol] = av;
        *(u16x8*)&Bs[srow][scol] = bv;
        __syncthreads();
        s16x8 a0 = *(const s16x8*)&As[wm * 32 + r][q * 8];
        s16x8 a1 = *(const s16x8*)&As[wm * 32 + 16 + r][q * 8];
        s16x8 b0 = *(const s16x8*)&Bs[wn * 32 + r][q * 8];
        s16x8 b1 = *(const s16x8*)&Bs[wn * 32 + 16 + r][q * 8];
        acc00 = __builtin_amdgcn_mfma_f32_16x16x32_bf16(a0, b0, acc00, 0, 0, 0);
        acc01 = __builtin_amdgcn_mfma_f32_16x16x32_bf16(a0, b1, acc01, 0, 0, 0);
        acc10 = __builtin_amdgcn_mfma_f32_16x16x32_bf16(a1, b0, acc10, 0, 0, 0);
        acc11 = __builtin_amdgcn_mfma_f32_16x16x32_bf16(a1, b1, acc11, 0, 0, 0);
    }
#pragma unroll
    for (int am = 0; am < 2; ++am) {
#pragma unroll
        for (int bn = 0; bn < 2; ++bn) {
            f32x4 a = am == 0 ? (bn == 0 ? acc00 : acc01) : (bn == 0 ? acc10 : acc11);
            int col = n0 + wn * 32 + bn * 16 + r;
            int rowb = m0 + wm * 32 + am * 16 + q * 4;
#pragma unroll
            for (int i = 0; i < 4; ++i) {
                float v = a[i];
                raw[(size_t)(rowb + i) * HID + col] = v;
                xcat[(size_t)(rowb + i) * KCAT + col] = f2bf(v);
            }
        }
    }
}

// ---------------------------------------------------------------- propagation
// One wave per node: y = scale * (A_hat x_in) - x_sub ; bf16 in/out within Xcat.
__global__ __launch_bounds__(256) void prop_kernel(unsigned short* xcat,
                                                   const int* __restrict__ rowptr,
                                                   const int* __restrict__ colidx,
                                                   const float* __restrict__ val,
                                                   int inOff, int outOff, int subOff,
                                                   float scale) {
    int g = blockIdx.x * 4 + (threadIdx.x >> 6);
    int lane = threadIdx.x & 63;
    int e = rowptr[g], e1 = rowptr[g + 1];
    float a0 = 0.f, a1 = 0.f, a2 = 0.f, a3 = 0.f;
    for (; e < e1; ++e) {
        int c = colidx[e];
        float v = val[e];
        u16x4 t = *(const u16x4*)(xcat + (size_t)c * KCAT + inOff + lane * 4);
        a0 += v * bf2f(t[0]);
        a1 += v * bf2f(t[1]);
        a2 += v * bf2f(t[2]);
        a3 += v * bf2f(t[3]);
    }
    a0 *= scale; a1 *= scale; a2 *= scale; a3 *= scale;
    if (subOff >= 0) {
        u16x4 p = *(const u16x4*)(xcat + (size_t)g * KCAT + subOff + lane * 4);
        a0 -= bf2f(p[0]); a1 -= bf2f(p[1]); a2 -= bf2f(p[2]); a3 -= bf2f(p[3]);
    }
    u16x4 o = {f2bf(a0), f2bf(a1), f2bf(a2), f2bf(a3)};
    *(u16x4*)(xcat + (size_t)g * KCAT + outOff + lane * 4) = o;
}

// ---------------------------------------------------------------- GEMM2
// pre = Xcat[40000x1280] @ Wcat[1280x256] + bias  -> d_out[seg_low] (fp32, pre-act)
// BM=64 BN=256 BK=32, 4 waves 1x4, wave tile 64x64 (4x4 frags).
__global__ __launch_bounds__(256) void gemm2_kernel(const unsigned short* __restrict__ xcat,
                                                    const unsigned short* __restrict__ Wt,
                                                    const float* __restrict__ bias,
                                                    float* __restrict__ outp) {
    __shared__ unsigned short As[64][32];
    __shared__ unsigned short Bs[256][32];
    const int m0 = blockIdx.x * 64;
    const int tid = threadIdx.x;
    const int lane = tid & 63, wn = tid >> 6;
    const int r = lane & 15, q = lane >> 4;
    const int srow = tid >> 2, scol = (tid & 3) * 8;

    f32x4 acc[4][4] = {};

    for (int kb = 0; kb < KCAT; kb += 32) {
        u16x8 av  = *(const u16x8*)(xcat + (size_t)(m0 + srow) * KCAT + kb + scol);
        u16x8 bv0 = *(const u16x8*)(Wt + (size_t)(srow)       * KCAT + kb + scol);
        u16x8 bv1 = *(const u16x8*)(Wt + (size_t)(srow +  64) * KCAT + kb + scol);
        u16x8 bv2 = *(const u16x8*)(Wt + (size_t)(srow + 128) * KCAT + kb + scol);
        u16x8 bv3 = *(const u16x8*)(Wt + (size_t)(srow + 192) * KCAT + kb + scol);
        __syncthreads();
        *(u16x8*)&As[srow][scol] = av;
        *(u16x8*)&Bs[srow][scol] = bv0;
        *(u16x8*)&Bs[srow + 64][scol] = bv1;
        *(u16x8*)&Bs[srow + 128][scol] = bv2;
        *(u16x8*)&Bs[srow + 192][scol] = bv3;
        __syncthreads();
        s16x8 af[4], bfv[4];
#pragma unroll
        for (int am = 0; am < 4; ++am) af[am] = *(const s16x8*)&As[am * 16 + r][q * 8];
#pragma unroll
        for (int bn = 0; bn < 4; ++bn) bfv[bn] = *(const s16x8*)&Bs[wn * 64 + bn * 16 + r][q * 8];
#pragma unroll
        for (int am = 0; am < 4; ++am) {
#pragma unroll
            for (int bn = 0; bn < 4; ++bn)
                acc[am][bn] = __builtin_amdgcn_mfma_f32_16x16x32_bf16(af[am], bfv[bn], acc[am][bn], 0, 0, 0);
        }
    }
#pragma unroll
    for (int am = 0; am < 4; ++am) {
        int rowb = m0 + am * 16 + q * 4;
#pragma unroll
        for (int bn = 0; bn < 4; ++bn) {
            int col = wn * 64 + bn * 16 + r;
            float bc = bias[col];
#pragma unroll
            for (int i = 0; i < 4; ++i)
                outp[(size_t)(rowb + i) * HID + col] = acc[am][bn][i] + bc;
        }
    }
}

// ---------------------------------------------------------------- GELU + LN (in place)
__global__ __launch_bounds__(256) void gelu_ln_kernel(float* __restrict__ out,
                                                      const float* __restrict__ gamma,
                                                      const float* __restrict__ beta) {
    int row = blockIdx.x * 4 + (threadIdx.x >> 6);
    int lane = threadIdx.x & 63;
    float* p = out + (size_t)row * HID + lane * 4;
    f32x4 x = *(f32x4*)p;
    f32x4 g;
#pragma unroll
    for (int i = 0; i < 4; ++i) g[i] = 0.5f * x[i] * (1.f + erff(x[i] * 0.70710678118654752f));
    float s = g[0] + g[1] + g[2] + g[3];
    float ss = g[0] * g[0] + g[1] * g[1] + g[2] * g[2] + g[3] * g[3];
#pragma unroll
    for (int off = 32; off > 0; off >>= 1) {
        s += __shfl_xor(s, off);
        ss += __shfl_xor(ss, off);
    }
    float mu = s * (1.f / HID);
    float var = ss * (1.f / HID) - mu * mu;
    float inv = rsqrtf(var + 1e-5f);
    f32x4 gm = *(const f32x4*)(gamma + lane * 4);
    f32x4 bt = *(const f32x4*)(beta + lane * 4);
#pragma unroll
    for (int i = 0; i < 4; ++i) x[i] = (g[i] - mu) * inv * gm[i] + bt[i];
    *(f32x4*)p = x;
}

// ---------------------------------------------------------------- launch
extern "C" void kernel_launch(void* const* d_in, const int* in_sizes, int n_in,
                              void* d_out, int out_size, void* d_ws, size_t ws_size,
                              hipStream_t stream) {
    const float* P     = (const float*)d_in[0];
    const float* S     = (const float*)d_in[1];
    const void*  E     = d_in[2];
    const float* W     = (const float*)d_in[3];
    const float* bias  = (const float*)d_in[4];
    const float* gamma = (const float*)d_in[5];
    const float* beta  = (const float*)d_in[6];

    float* out = (float*)d_out;            // seg_low [40000*256]
    float* raw = out + (size_t)NSEG * HID; // seg_low_raw [40000*256]

    char* ws = (char*)d_ws;
    size_t off = 0;
    auto alloc = [&](size_t bytes) -> void* {
        void* p = ws + off;
        off += (bytes + 255) & ~(size_t)255;
        return p;
    };
    unsigned short* xcat   = (unsigned short*)alloc((size_t)NSEG * KCAT * 2);
    unsigned short* Pt     = (unsigned short*)alloc((size_t)HID * NREG * 2);
    unsigned short* Wt     = (unsigned short*)alloc((size_t)HID * KCAT * 2);
    int*            deg    = (int*)alloc((size_t)NSEG * 4);
    float*          dinv   = (float*)alloc((size_t)NSEG * 4);
    int*            cnt    = (int*)alloc((size_t)NSEG * 4);
    int*            rowptr = (int*)alloc((size_t)(NSEG + 1) * 4);
    int*            cursor = (int*)alloc((size_t)NSEG * 4);
    int*            colidx = (int*)alloc((size_t)NEDGE * 4);
    float*          val    = (float*)alloc((size_t)NEDGE * 4);
    int*            flag   = (int*)alloc(256);
    if (off > ws_size) return;  // workspace too small: fail loudly via wrong output

    hipMemsetAsync(deg, 0, (size_t)NSEG * 4, stream);
    hipMemsetAsync(cnt, 0, (size_t)NSEG * 4, stream);

    detect_kernel<<<1, 64, 0, stream>>>((const unsigned int*)E, flag);
    prep_pt_kernel<<<HID, 256, 0, stream>>>(P, Pt);
    prep_wt_kernel<<<HID, 256, 0, stream>>>(W, Wt);

    deg_cnt_kernel<<<NEDGE / 256, 256, 0, stream>>>(E, flag, deg, cnt);
    dinv_kernel<<<(NSEG + 255) / 256, 256, 0, stream>>>(deg, dinv);
    scan_kernel<<<1, 1024, 0, stream>>>(cnt, rowptr, cursor);
    scatter_kernel<<<NEDGE / 256, 256, 0, stream>>>(E, flag, dinv, cursor, colidx, val);

    gemm1_kernel<<<dim3(NSEG / 64, HID / 64), 256, 0, stream>>>(S, Pt, raw, xcat);

    // Tx1 = prop(Tx0)
    prop_kernel<<<NSEG / 4, 256, 0, stream>>>(xcat, rowptr, colidx, val, 0 * HID, 1 * HID, -1, 1.f);
    // Tx2 = 2*prop(Tx1) - Tx0
    prop_kernel<<<NSEG / 4, 256, 0, stream>>>(xcat, rowptr, colidx, val, 1 * HID, 2 * HID, 0 * HID, 2.f);
    // Tx3 = 2*prop(Tx2) - Tx1
    prop_kernel<<<NSEG / 4, 256, 0, stream>>>(xcat, rowptr, colidx, val, 2 * HID, 3 * HID, 1 * HID, 2.f);
    // Tx4 = 2*prop(Tx3) - Tx2
    prop_kernel<<<NSEG / 4, 256, 0, stream>>>(xcat, rowptr, colidx, val, 3 * HID, 4 * HID, 2 * HID, 2.f);

    gemm2_kernel<<<NSEG / 64, 256, 0, stream>>>(xcat, Wt, bias, out);
    gelu_ln_kernel<<<NSEG / 4, 256, 0, stream>>>(out, gamma, beta);
}

// Round 2
// 554.144 us; speedup vs baseline: 1.2735x; 1.2735x over previous
//
#include <hip/hip_runtime.h>

#define NSEG 40000
#define NREG 1000
#define NEDGE 640000
#define HID 256
#define KCAT 1280   // 5 * HID
#define LPAD 40     // LDS row stride in bf16 elems (80 B = 5x16B granules -> conflict-free b128)

typedef float f32x4 __attribute__((ext_vector_type(4)));
typedef short s16x8 __attribute__((ext_vector_type(8)));
typedef unsigned short u16x4 __attribute__((ext_vector_type(4)));
typedef unsigned short u16x8 __attribute__((ext_vector_type(8)));

__device__ __forceinline__ unsigned short f2bf(float f) {
    unsigned u = __builtin_bit_cast(unsigned, f);
    u += 0x7FFFu + ((u >> 16) & 1u);   // round-to-nearest-even
    return (unsigned short)(u >> 16);
}
__device__ __forceinline__ float bf2f(unsigned short h) {
    unsigned u = ((unsigned)h) << 16;
    return __builtin_bit_cast(float, u);
}

// ---------------------------------------------------------------- edge dtype
__global__ void detect_kernel(const unsigned int* __restrict__ E, int* flag) {
    int lane = threadIdx.x;
    unsigned v = E[2 * lane + 1];
    unsigned long long m = __ballot(v == 0u);
    if (lane == 0) *flag = (__popcll(m) >= 48) ? 1 : 0;
}

__device__ __forceinline__ int edge_at(const void* E, int idx, int is64) {
    return is64 ? (int)((const long long*)E)[idx] : ((const int*)E)[idx];
}

// ---------------------------------------------------------------- CSR build
__global__ __launch_bounds__(256) void deg_cnt_kernel(const void* __restrict__ E,
                                                      const int* __restrict__ flag,
                                                      int* deg, int* cnt) {
    int e = blockIdx.x * 256 + threadIdx.x;
    if (e >= NEDGE) return;
    int is64 = *flag;
    int s = edge_at(E, e, is64);
    int d = edge_at(E, e + NEDGE, is64);
    if (s != d) {
        atomicAdd(&deg[s], 1);
        atomicAdd(&cnt[d], 1);
    }
}

__global__ __launch_bounds__(256) void dinv_kernel(const int* __restrict__ deg,
                                                   float* __restrict__ dinv) {
    int i = blockIdx.x * 256 + threadIdx.x;
    if (i < NSEG) {
        int d = deg[i];
        dinv[i] = d > 0 ? rsqrtf((float)d) : 0.f;
    }
}

__global__ __launch_bounds__(1024) void scan_kernel(const int* __restrict__ cnt,
                                                    int* __restrict__ rowptr,
                                                    int* __restrict__ cursor) {
    __shared__ int ps[1024];
    const int t = threadIdx.x;
    const int CH = 40;  // 1024*40 >= 40000
    int base = t * CH;
    int s = 0;
    for (int i = 0; i < CH; ++i) {
        int idx = base + i;
        if (idx < NSEG) s += cnt[idx];
    }
    ps[t] = s;
    __syncthreads();
    for (int off = 1; off < 1024; off <<= 1) {
        int v = 0;
        if (t >= off) v = ps[t - off];
        __syncthreads();
        if (t >= off) ps[t] += v;
        __syncthreads();
    }
    int run = (t == 0) ? 0 : ps[t - 1];
    for (int i = 0; i < CH; ++i) {
        int idx = base + i;
        if (idx < NSEG) {
            rowptr[idx] = run;
            cursor[idx] = run;
            run += cnt[idx];
        }
    }
    if (t == 1023) rowptr[NSEG] = ps[1023];
}

__global__ __launch_bounds__(256) void scatter_kernel(const void* __restrict__ E,
                                                      const int* __restrict__ flag,
                                                      const float* __restrict__ dinv,
                                                      int* cursor,
                                                      int* __restrict__ colidx,
                                                      float* __restrict__ val) {
    int e = blockIdx.x * 256 + threadIdx.x;
    if (e >= NEDGE) return;
    int is64 = *flag;
    int s = edge_at(E, e, is64);
    int d = edge_at(E, e + NEDGE, is64);
    if (s != d) {
        int pos = atomicAdd(&cursor[d], 1);
        colidx[pos] = s;
        val[pos] = -dinv[s] * dinv[d];
    }
}

// ---------------------------------------------------------------- weight prep
__global__ void prep_pt_kernel(const float* __restrict__ P, unsigned short* __restrict__ Pt) {
    int n = blockIdx.x;
    for (int k = threadIdx.x; k < NREG; k += blockDim.x)
        Pt[(size_t)n * NREG + k] = f2bf(P[(size_t)k * HID + n]);
}
__global__ void prep_wt_kernel(const float* __restrict__ W, unsigned short* __restrict__ Wt) {
    int n = blockIdx.x;
    for (int k = threadIdx.x; k < KCAT; k += blockDim.x)
        Wt[(size_t)n * KCAT + k] = f2bf(W[(size_t)k * HID + n]);
}

// ---------------------------------------------------------------- GEMM1
// raw = S @ P ; bf16 copy into Xcat seg 0.  BM=64 BN=256 BK=32 (S fetched ONCE).
// 4 waves 1x4 over N, wave tile 64x64 (4x4 16x16x32 frags).
__global__ __launch_bounds__(256) void gemm1_kernel(const float* __restrict__ S,
                                                    const unsigned short* __restrict__ Pt,
                                                    float* __restrict__ raw,
                                                    unsigned short* __restrict__ xcat) {
    __shared__ unsigned short As[64][LPAD];
    __shared__ unsigned short Bs[256][LPAD];
    const int m0 = blockIdx.x * 64;
    const int tid = threadIdx.x;
    const int lane = tid & 63, wn = tid >> 6;
    const int r = lane & 15, q = lane >> 4;
    const int srow = tid >> 2, scol = (tid & 3) * 8;

    f32x4 acc[4][4] = {};

    for (int kb = 0; kb < NREG; kb += 32) {
        const bool kvalid = (kb + scol + 8 <= NREG);  // NREG % 8 == 0
        u16x8 av = {0, 0, 0, 0, 0, 0, 0, 0};
        u16x8 bv0 = av, bv1 = av, bv2 = av, bv3 = av;
        if (kvalid) {
            const float* sp = S + (size_t)(m0 + srow) * NREG + kb + scol;
            f32x4 f0 = *(const f32x4*)sp;
            f32x4 f1 = *(const f32x4*)(sp + 4);
            av[0] = f2bf(f0[0]); av[1] = f2bf(f0[1]); av[2] = f2bf(f0[2]); av[3] = f2bf(f0[3]);
            av[4] = f2bf(f1[0]); av[5] = f2bf(f1[1]); av[6] = f2bf(f1[2]); av[7] = f2bf(f1[3]);
            bv0 = *(const u16x8*)(Pt + (size_t)(srow)       * NREG + kb + scol);
            bv1 = *(const u16x8*)(Pt + (size_t)(srow +  64) * NREG + kb + scol);
            bv2 = *(const u16x8*)(Pt + (size_t)(srow + 128) * NREG + kb + scol);
            bv3 = *(const u16x8*)(Pt + (size_t)(srow + 192) * NREG + kb + scol);
        }
        __syncthreads();
        *(u16x8*)&As[srow][scol] = av;
        *(u16x8*)&Bs[srow][scol] = bv0;
        *(u16x8*)&Bs[srow + 64][scol] = bv1;
        *(u16x8*)&Bs[srow + 128][scol] = bv2;
        *(u16x8*)&Bs[srow + 192][scol] = bv3;
        __syncthreads();
        s16x8 af[4], bfv[4];
#pragma unroll
        for (int am = 0; am < 4; ++am) af[am] = *(const s16x8*)&As[am * 16 + r][q * 8];
#pragma unroll
        for (int bn = 0; bn < 4; ++bn) bfv[bn] = *(const s16x8*)&Bs[wn * 64 + bn * 16 + r][q * 8];
#pragma unroll
        for (int am = 0; am < 4; ++am) {
#pragma unroll
            for (int bn = 0; bn < 4; ++bn)
                acc[am][bn] = __builtin_amdgcn_mfma_f32_16x16x32_bf16(af[am], bfv[bn], acc[am][bn], 0, 0, 0);
        }
    }
#pragma unroll
    for (int am = 0; am < 4; ++am) {
        int rowb = m0 + am * 16 + q * 4;
#pragma unroll
        for (int bn = 0; bn < 4; ++bn) {
            int col = wn * 64 + bn * 16 + r;
#pragma unroll
            for (int i = 0; i < 4; ++i) {
                float v = acc[am][bn][i];
                raw[(size_t)(rowb + i) * HID + col] = v;
                xcat[(size_t)(rowb + i) * KCAT + col] = f2bf(v);
            }
        }
    }
}

// ---------------------------------------------------------------- propagation
// One wave per node. Cooperative (colidx,val) load + shfl broadcast; 8-wide
// unrolled gathers so 8 independent 512B row-gathers are in flight per wave.
__global__ __launch_bounds__(256) void prop_kernel(unsigned short* xcat,
                                                   const int* __restrict__ rowptr,
                                                   const int* __restrict__ colidx,
                                                   const float* __restrict__ val,
                                                   int inOff, int outOff, int subOff,
                                                   float scale) {
    int g = blockIdx.x * 4 + (threadIdx.x >> 6);
    int lane = threadIdx.x & 63;
    int e0 = rowptr[g], e1 = rowptr[g + 1];
    float a0 = 0.f, a1 = 0.f, a2 = 0.f, a3 = 0.f;
    const unsigned short* xin = xcat + inOff + lane * 4;
    for (int base = e0; base < e1; base += 64) {
        int m = e1 - base;
        if (m > 64) m = 64;
        int cc = 0;
        float vv = 0.f;
        if (lane < m) {
            cc = colidx[base + lane];
            vv = val[base + lane];
        }
        int i = 0;
        for (; i + 8 <= m; i += 8) {
            u16x4 t[8];
#pragma unroll
            for (int j = 0; j < 8; ++j) {
                int c = __shfl(cc, i + j);
                t[j] = *(const u16x4*)(xin + (size_t)c * KCAT);
            }
#pragma unroll
            for (int j = 0; j < 8; ++j) {
                float v = __shfl(vv, i + j);
                a0 += v * bf2f(t[j][0]);
                a1 += v * bf2f(t[j][1]);
                a2 += v * bf2f(t[j][2]);
                a3 += v * bf2f(t[j][3]);
            }
        }
        for (; i < m; ++i) {
            int c = __shfl(cc, i);
            float v = __shfl(vv, i);
            u16x4 t = *(const u16x4*)(xin + (size_t)c * KCAT);
            a0 += v * bf2f(t[0]);
            a1 += v * bf2f(t[1]);
            a2 += v * bf2f(t[2]);
            a3 += v * bf2f(t[3]);
        }
    }
    a0 *= scale; a1 *= scale; a2 *= scale; a3 *= scale;
    if (subOff >= 0) {
        u16x4 p = *(const u16x4*)(xcat + (size_t)g * KCAT + subOff + lane * 4);
        a0 -= bf2f(p[0]); a1 -= bf2f(p[1]); a2 -= bf2f(p[2]); a3 -= bf2f(p[3]);
    }
    u16x4 o = {f2bf(a0), f2bf(a1), f2bf(a2), f2bf(a3)};
    *(u16x4*)(xcat + (size_t)g * KCAT + outOff + lane * 4) = o;
}

// ---------------------------------------------------------------- GEMM2
// pre = Xcat @ Wcat + bias -> d_out[seg_low] (fp32, pre-activation)
__global__ __launch_bounds__(256) void gemm2_kernel(const unsigned short* __restrict__ xcat,
                                                    const unsigned short* __restrict__ Wt,
                                                    const float* __restrict__ bias,
                                                    float* __restrict__ outp) {
    __shared__ unsigned short As[64][LPAD];
    __shared__ unsigned short Bs[256][LPAD];
    const int m0 = blockIdx.x * 64;
    const int tid = threadIdx.x;
    const int lane = tid & 63, wn = tid >> 6;
    const int r = lane & 15, q = lane >> 4;
    const int srow = tid >> 2, scol = (tid & 3) * 8;

    f32x4 acc[4][4] = {};

    for (int kb = 0; kb < KCAT; kb += 32) {
        u16x8 av  = *(const u16x8*)(xcat + (size_t)(m0 + srow) * KCAT + kb + scol);
        u16x8 bv0 = *(const u16x8*)(Wt + (size_t)(srow)       * KCAT + kb + scol);
        u16x8 bv1 = *(const u16x8*)(Wt + (size_t)(srow +  64) * KCAT + kb + scol);
        u16x8 bv2 = *(const u16x8*)(Wt + (size_t)(srow + 128) * KCAT + kb + scol);
        u16x8 bv3 = *(const u16x8*)(Wt + (size_t)(srow + 192) * KCAT + kb + scol);
        __syncthreads();
        *(u16x8*)&As[srow][scol] = av;
        *(u16x8*)&Bs[srow][scol] = bv0;
        *(u16x8*)&Bs[srow + 64][scol] = bv1;
        *(u16x8*)&Bs[srow + 128][scol] = bv2;
        *(u16x8*)&Bs[srow + 192][scol] = bv3;
        __syncthreads();
        s16x8 af[4], bfv[4];
#pragma unroll
        for (int am = 0; am < 4; ++am) af[am] = *(const s16x8*)&As[am * 16 + r][q * 8];
#pragma unroll
        for (int bn = 0; bn < 4; ++bn) bfv[bn] = *(const s16x8*)&Bs[wn * 64 + bn * 16 + r][q * 8];
#pragma unroll
        for (int am = 0; am < 4; ++am) {
#pragma unroll
            for (int bn = 0; bn < 4; ++bn)
                acc[am][bn] = __builtin_amdgcn_mfma_f32_16x16x32_bf16(af[am], bfv[bn], acc[am][bn], 0, 0, 0);
        }
    }
#pragma unroll
    for (int am = 0; am < 4; ++am) {
        int rowb = m0 + am * 16 + q * 4;
#pragma unroll
        for (int bn = 0; bn < 4; ++bn) {
            int col = wn * 64 + bn * 16 + r;
            float bc = bias[col];
#pragma unroll
            for (int i = 0; i < 4; ++i)
                outp[(size_t)(rowb + i) * HID + col] = acc[am][bn][i] + bc;
        }
    }
}

// ---------------------------------------------------------------- GELU + LN (in place)
__global__ __launch_bounds__(256) void gelu_ln_kernel(float* __restrict__ out,
                                                      const float* __restrict__ gamma,
                                                      const float* __restrict__ beta) {
    int row = blockIdx.x * 4 + (threadIdx.x >> 6);
    int lane = threadIdx.x & 63;
    float* p = out + (size_t)row * HID + lane * 4;
    f32x4 x = *(f32x4*)p;
    f32x4 g;
#pragma unroll
    for (int i = 0; i < 4; ++i) g[i] = 0.5f * x[i] * (1.f + erff(x[i] * 0.70710678118654752f));
    float s = g[0] + g[1] + g[2] + g[3];
    float ss = g[0] * g[0] + g[1] * g[1] + g[2] * g[2] + g[3] * g[3];
#pragma unroll
    for (int off = 32; off > 0; off >>= 1) {
        s += __shfl_xor(s, off);
        ss += __shfl_xor(ss, off);
    }
    float mu = s * (1.f / HID);
    float var = ss * (1.f / HID) - mu * mu;
    float inv = rsqrtf(var + 1e-5f);
    f32x4 gm = *(const f32x4*)(gamma + lane * 4);
    f32x4 bt = *(const f32x4*)(beta + lane * 4);
#pragma unroll
    for (int i = 0; i < 4; ++i) x[i] = (g[i] - mu) * inv * gm[i] + bt[i];
    *(f32x4*)p = x;
}

// ---------------------------------------------------------------- launch
extern "C" void kernel_launch(void* const* d_in, const int* in_sizes, int n_in,
                              void* d_out, int out_size, void* d_ws, size_t ws_size,
                              hipStream_t stream) {
    const float* P     = (const float*)d_in[0];
    const float* S     = (const float*)d_in[1];
    const void*  E     = d_in[2];
    const float* W     = (const float*)d_in[3];
    const float* bias  = (const float*)d_in[4];
    const float* gamma = (const float*)d_in[5];
    const float* beta  = (const float*)d_in[6];

    float* out = (float*)d_out;            // seg_low [40000*256]
    float* raw = out + (size_t)NSEG * HID; // seg_low_raw [40000*256]

    char* ws = (char*)d_ws;
    size_t off = 0;
    auto alloc = [&](size_t bytes) -> void* {
        void* p = ws + off;
        off += (bytes + 255) & ~(size_t)255;
        return p;
    };
    unsigned short* xcat   = (unsigned short*)alloc((size_t)NSEG * KCAT * 2);
    unsigned short* Pt     = (unsigned short*)alloc((size_t)HID * NREG * 2);
    unsigned short* Wt     = (unsigned short*)alloc((size_t)HID * KCAT * 2);
    int*            deg    = (int*)alloc((size_t)NSEG * 4);
    float*          dinv   = (float*)alloc((size_t)NSEG * 4);
    int*            cnt    = (int*)alloc((size_t)NSEG * 4);
    int*            rowptr = (int*)alloc((size_t)(NSEG + 1) * 4);
    int*            cursor = (int*)alloc((size_t)NSEG * 4);
    int*            colidx = (int*)alloc((size_t)NEDGE * 4);
    float*          val    = (float*)alloc((size_t)NEDGE * 4);
    int*            flag   = (int*)alloc(256);
    if (off > ws_size) return;

    hipMemsetAsync(deg, 0, (size_t)NSEG * 4, stream);
    hipMemsetAsync(cnt, 0, (size_t)NSEG * 4, stream);

    detect_kernel<<<1, 64, 0, stream>>>((const unsigned int*)E, flag);
    prep_pt_kernel<<<HID, 256, 0, stream>>>(P, Pt);
    prep_wt_kernel<<<HID, 256, 0, stream>>>(W, Wt);

    deg_cnt_kernel<<<NEDGE / 256, 256, 0, stream>>>(E, flag, deg, cnt);
    dinv_kernel<<<(NSEG + 255) / 256, 256, 0, stream>>>(deg, dinv);
    scan_kernel<<<1, 1024, 0, stream>>>(cnt, rowptr, cursor);
    scatter_kernel<<<NEDGE / 256, 256, 0, stream>>>(E, flag, dinv, cursor, colidx, val);

    gemm1_kernel<<<NSEG / 64, 256, 0, stream>>>(S, Pt, raw, xcat);

    prop_kernel<<<NSEG / 4, 256, 0, stream>>>(xcat, rowptr, colidx, val, 0 * HID, 1 * HID, -1, 1.f);
    prop_kernel<<<NSEG / 4, 256, 0, stream>>>(xcat, rowptr, colidx, val, 1 * HID, 2 * HID, 0 * HID, 2.f);
    prop_kernel<<<NSEG / 4, 256, 0, stream>>>(xcat, rowptr, colidx, val, 2 * HID, 3 * HID, 1 * HID, 2.f);
    prop_kernel<<<NSEG / 4, 256, 0, stream>>>(xcat, rowptr, colidx, val, 3 * HID, 4 * HID, 2 * HID, 2.f);

    gemm2_kernel<<<NSEG / 64, 256, 0, stream>>>(xcat, Wt, bias, out);
    gelu_ln_kernel<<<NSEG / 4, 256, 0, stream>>>(out, gamma, beta);
}

// Round 3
// 469.717 us; speedup vs baseline: 1.5024x; 1.1797x over previous
//
#include <hip/hip_runtime.h>

#define NSEG 40000
#define NREG 1000
#define NEDGE 640000
#define HID 256
#define KCAT 1280   // 5 * HID
#define LPAD 40     // LDS row stride in bf16 elems (80 B = 5x16B granules -> conflict-free b128)
#define NBLK 157    // ceil(NSEG/256)

typedef float f32x4 __attribute__((ext_vector_type(4)));
typedef short s16x8 __attribute__((ext_vector_type(8)));
typedef unsigned short u16x4 __attribute__((ext_vector_type(4)));
typedef unsigned short u16x8 __attribute__((ext_vector_type(8)));

__device__ __forceinline__ unsigned short f2bf(float f) {
    unsigned u = __builtin_bit_cast(unsigned, f);
    u += 0x7FFFu + ((u >> 16) & 1u);   // round-to-nearest-even
    return (unsigned short)(u >> 16);
}
__device__ __forceinline__ float bf2f(unsigned short h) {
    unsigned u = ((unsigned)h) << 16;
    return __builtin_bit_cast(float, u);
}

// ---------------------------------------------------------------- edge dtype
__global__ void detect_kernel(const unsigned int* __restrict__ E, int* flag) {
    int lane = threadIdx.x;
    unsigned v = E[2 * lane + 1];
    unsigned long long m = __ballot(v == 0u);
    if (lane == 0) *flag = (__popcll(m) >= 48) ? 1 : 0;
}

__device__ __forceinline__ int edge_at(const void* E, int idx, int is64) {
    return is64 ? (int)((const long long*)E)[idx] : ((const int*)E)[idx];
}

// ---------------------------------------------------------------- CSR build
__global__ __launch_bounds__(256) void deg_cnt_kernel(const void* __restrict__ E,
                                                      const int* __restrict__ flag,
                                                      int* deg, int* cnt) {
    int e = blockIdx.x * 256 + threadIdx.x;
    if (e >= NEDGE) return;
    int is64 = *flag;
    int s = edge_at(E, e, is64);
    int d = edge_at(E, e + NEDGE, is64);
    if (s != d) {
        atomicAdd(&deg[s], 1);
        atomicAdd(&cnt[d], 1);
    }
}

__global__ __launch_bounds__(256) void dinv_kernel(const int* __restrict__ deg,
                                                   float* __restrict__ dinv) {
    int i = blockIdx.x * 256 + threadIdx.x;
    if (i < NSEG) {
        int d = deg[i];
        dinv[i] = d > 0 ? rsqrtf((float)d) : 0.f;
    }
}

// --- hierarchical scan: block sums -> scan sums -> local scan + offset
__global__ __launch_bounds__(256) void scan1_kernel(const int* __restrict__ cnt,
                                                    int* __restrict__ bsum) {
    __shared__ int sh[256];
    int t = threadIdx.x;
    int i = blockIdx.x * 256 + t;
    sh[t] = (i < NSEG) ? cnt[i] : 0;
    __syncthreads();
    for (int o = 128; o > 0; o >>= 1) {
        if (t < o) sh[t] += sh[t + o];
        __syncthreads();
    }
    if (t == 0) bsum[blockIdx.x] = sh[0];
}

__global__ __launch_bounds__(256) void scan2_kernel(const int* __restrict__ bsum,
                                                    int* __restrict__ boff,
                                                    int* __restrict__ rowptr) {
    __shared__ int sh[256];
    int t = threadIdx.x;
    int v = (t < NBLK) ? bsum[t] : 0;
    sh[t] = v;
    __syncthreads();
    for (int o = 1; o < 256; o <<= 1) {
        int x = 0;
        if (t >= o) x = sh[t - o];
        __syncthreads();
        if (t >= o) sh[t] += x;
        __syncthreads();
    }
    if (t < NBLK) boff[t] = sh[t] - v;       // exclusive
    if (t == 255) rowptr[NSEG] = sh[255];    // total
}

__global__ __launch_bounds__(256) void scan3_kernel(const int* __restrict__ cnt,
                                                    const int* __restrict__ boff,
                                                    int* __restrict__ rowptr,
                                                    int* __restrict__ cursor) {
    __shared__ int sh[256];
    int t = threadIdx.x;
    int i = blockIdx.x * 256 + t;
    int v = (i < NSEG) ? cnt[i] : 0;
    sh[t] = v;
    __syncthreads();
    for (int o = 1; o < 256; o <<= 1) {
        int x = 0;
        if (t >= o) x = sh[t - o];
        __syncthreads();
        if (t >= o) sh[t] += x;
        __syncthreads();
    }
    if (i < NSEG) {
        int p = boff[blockIdx.x] + sh[t] - v;
        rowptr[i] = p;
        cursor[i] = p;
    }
}

__global__ __launch_bounds__(256) void scatter_kernel(const void* __restrict__ E,
                                                      const int* __restrict__ flag,
                                                      const float* __restrict__ dinv,
                                                      int* cursor,
                                                      int* __restrict__ colidx,
                                                      float* __restrict__ val) {
    int e = blockIdx.x * 256 + threadIdx.x;
    if (e >= NEDGE) return;
    int is64 = *flag;
    int s = edge_at(E, e, is64);
    int d = edge_at(E, e + NEDGE, is64);
    if (s != d) {
        int pos = atomicAdd(&cursor[d], 1);
        colidx[pos] = s;
        val[pos] = -dinv[s] * dinv[d];
    }
}

// ---------------------------------------------------------------- weight prep
__global__ void prep_pt_kernel(const float* __restrict__ P, unsigned short* __restrict__ Pt) {
    int n = blockIdx.x;
    for (int k = threadIdx.x; k < NREG; k += blockDim.x)
        Pt[(size_t)n * NREG + k] = f2bf(P[(size_t)k * HID + n]);
}
__global__ void prep_wt_kernel(const float* __restrict__ W, unsigned short* __restrict__ Wt) {
    int n = blockIdx.x;
    for (int k = threadIdx.x; k < KCAT; k += blockDim.x)
        Wt[(size_t)n * KCAT + k] = f2bf(W[(size_t)k * HID + n]);
}

// ---------------------------------------------------------------- GEMM1
// raw = S @ P ; bf16 copy into Xcat seg 0.  BM=64 BN=256 BK=32 (S fetched ONCE).
__global__ __launch_bounds__(256) void gemm1_kernel(const float* __restrict__ S,
                                                    const unsigned short* __restrict__ Pt,
                                                    float* __restrict__ raw,
                                                    unsigned short* __restrict__ xcat) {
    __shared__ unsigned short As[64][LPAD];
    __shared__ unsigned short Bs[256][LPAD];
    const int m0 = blockIdx.x * 64;
    const int tid = threadIdx.x;
    const int lane = tid & 63, wn = tid >> 6;
    const int r = lane & 15, q = lane >> 4;
    const int srow = tid >> 2, scol = (tid & 3) * 8;

    f32x4 acc[4][4] = {};

    for (int kb = 0; kb < NREG; kb += 32) {
        const bool kvalid = (kb + scol + 8 <= NREG);  // NREG % 8 == 0
        u16x8 av = {0, 0, 0, 0, 0, 0, 0, 0};
        u16x8 bv0 = av, bv1 = av, bv2 = av, bv3 = av;
        if (kvalid) {
            const float* sp = S + (size_t)(m0 + srow) * NREG + kb + scol;
            f32x4 f0 = *(const f32x4*)sp;
            f32x4 f1 = *(const f32x4*)(sp + 4);
            av[0] = f2bf(f0[0]); av[1] = f2bf(f0[1]); av[2] = f2bf(f0[2]); av[3] = f2bf(f0[3]);
            av[4] = f2bf(f1[0]); av[5] = f2bf(f1[1]); av[6] = f2bf(f1[2]); av[7] = f2bf(f1[3]);
            bv0 = *(const u16x8*)(Pt + (size_t)(srow)       * NREG + kb + scol);
            bv1 = *(const u16x8*)(Pt + (size_t)(srow +  64) * NREG + kb + scol);
            bv2 = *(const u16x8*)(Pt + (size_t)(srow + 128) * NREG + kb + scol);
            bv3 = *(const u16x8*)(Pt + (size_t)(srow + 192) * NREG + kb + scol);
        }
        __syncthreads();
        *(u16x8*)&As[srow][scol] = av;
        *(u16x8*)&Bs[srow][scol] = bv0;
        *(u16x8*)&Bs[srow + 64][scol] = bv1;
        *(u16x8*)&Bs[srow + 128][scol] = bv2;
        *(u16x8*)&Bs[srow + 192][scol] = bv3;
        __syncthreads();
        s16x8 af[4], bfv[4];
#pragma unroll
        for (int am = 0; am < 4; ++am) af[am] = *(const s16x8*)&As[am * 16 + r][q * 8];
#pragma unroll
        for (int bn = 0; bn < 4; ++bn) bfv[bn] = *(const s16x8*)&Bs[wn * 64 + bn * 16 + r][q * 8];
#pragma unroll
        for (int am = 0; am < 4; ++am) {
#pragma unroll
            for (int bn = 0; bn < 4; ++bn)
                acc[am][bn] = __builtin_amdgcn_mfma_f32_16x16x32_bf16(af[am], bfv[bn], acc[am][bn], 0, 0, 0);
        }
    }
#pragma unroll
    for (int am = 0; am < 4; ++am) {
        int rowb = m0 + am * 16 + q * 4;
#pragma unroll
        for (int bn = 0; bn < 4; ++bn) {
            int col = wn * 64 + bn * 16 + r;
#pragma unroll
            for (int i = 0; i < 4; ++i) {
                float v = acc[am][bn][i];
                raw[(size_t)(rowb + i) * HID + col] = v;
                xcat[(size_t)(rowb + i) * KCAT + col] = f2bf(v);
            }
        }
    }
}

// ---------------------------------------------------------------- propagation
__global__ __launch_bounds__(256) void prop_kernel(unsigned short* xcat,
                                                   const int* __restrict__ rowptr,
                                                   const int* __restrict__ colidx,
                                                   const float* __restrict__ val,
                                                   int inOff, int outOff, int subOff,
                                                   float scale) {
    int g = blockIdx.x * 4 + (threadIdx.x >> 6);
    int lane = threadIdx.x & 63;
    int e0 = rowptr[g], e1 = rowptr[g + 1];
    float a0 = 0.f, a1 = 0.f, a2 = 0.f, a3 = 0.f;
    const unsigned short* xin = xcat + inOff + lane * 4;
    for (int base = e0; base < e1; base += 64) {
        int m = e1 - base;
        if (m > 64) m = 64;
        int cc = 0;
        float vv = 0.f;
        if (lane < m) {
            cc = colidx[base + lane];
            vv = val[base + lane];
        }
        int i = 0;
        for (; i + 8 <= m; i += 8) {
            u16x4 t[8];
#pragma unroll
            for (int j = 0; j < 8; ++j) {
                int c = __shfl(cc, i + j);
                t[j] = *(const u16x4*)(xin + (size_t)c * KCAT);
            }
#pragma unroll
            for (int j = 0; j < 8; ++j) {
                float v = __shfl(vv, i + j);
                a0 += v * bf2f(t[j][0]);
                a1 += v * bf2f(t[j][1]);
                a2 += v * bf2f(t[j][2]);
                a3 += v * bf2f(t[j][3]);
            }
        }
        for (; i < m; ++i) {
            int c = __shfl(cc, i);
            float v = __shfl(vv, i);
            u16x4 t = *(const u16x4*)(xin + (size_t)c * KCAT);
            a0 += v * bf2f(t[0]);
            a1 += v * bf2f(t[1]);
            a2 += v * bf2f(t[2]);
            a3 += v * bf2f(t[3]);
        }
    }
    a0 *= scale; a1 *= scale; a2 *= scale; a3 *= scale;
    if (subOff >= 0) {
        u16x4 p = *(const u16x4*)(xcat + (size_t)g * KCAT + subOff + lane * 4);
        a0 -= bf2f(p[0]); a1 -= bf2f(p[1]); a2 -= bf2f(p[2]); a3 -= bf2f(p[3]);
    }
    u16x4 o = {f2bf(a0), f2bf(a1), f2bf(a2), f2bf(a3)};
    *(u16x4*)(xcat + (size_t)g * KCAT + outOff + lane * 4) = o;
}

// ---------------------------------------------------------------- GEMM2 + GELU + LN (fused)
// pre = Xcat @ Wcat + bias; out = LN(GELU(pre)). Block covers full 256-col rows,
// so LN stats are block-local: shfl-reduce over r lanes + 2KB LDS cross-wave.
__global__ __launch_bounds__(256) void gemm2_kernel(const unsigned short* __restrict__ xcat,
                                                    const unsigned short* __restrict__ Wt,
                                                    const float* __restrict__ bias,
                                                    const float* __restrict__ gamma,
                                                    const float* __restrict__ beta,
                                                    float* __restrict__ outp) {
    __shared__ unsigned short As[64][LPAD];
    __shared__ unsigned short Bs[256][LPAD];
    __shared__ float rs[64][4];
    __shared__ float rss[64][4];
    const int m0 = blockIdx.x * 64;
    const int tid = threadIdx.x;
    const int lane = tid & 63, wn = tid >> 6;
    const int r = lane & 15, q = lane >> 4;
    const int srow = tid >> 2, scol = (tid & 3) * 8;

    f32x4 acc[4][4] = {};

    for (int kb = 0; kb < KCAT; kb += 32) {
        u16x8 av  = *(const u16x8*)(xcat + (size_t)(m0 + srow) * KCAT + kb + scol);
        u16x8 bv0 = *(const u16x8*)(Wt + (size_t)(srow)       * KCAT + kb + scol);
        u16x8 bv1 = *(const u16x8*)(Wt + (size_t)(srow +  64) * KCAT + kb + scol);
        u16x8 bv2 = *(const u16x8*)(Wt + (size_t)(srow + 128) * KCAT + kb + scol);
        u16x8 bv3 = *(const u16x8*)(Wt + (size_t)(srow + 192) * KCAT + kb + scol);
        __syncthreads();
        *(u16x8*)&As[srow][scol] = av;
        *(u16x8*)&Bs[srow][scol] = bv0;
        *(u16x8*)&Bs[srow + 64][scol] = bv1;
        *(u16x8*)&Bs[srow + 128][scol] = bv2;
        *(u16x8*)&Bs[srow + 192][scol] = bv3;
        __syncthreads();
        s16x8 af[4], bfv[4];
#pragma unroll
        for (int am = 0; am < 4; ++am) af[am] = *(const s16x8*)&As[am * 16 + r][q * 8];
#pragma unroll
        for (int bn = 0; bn < 4; ++bn) bfv[bn] = *(const s16x8*)&Bs[wn * 64 + bn * 16 + r][q * 8];
#pragma unroll
        for (int am = 0; am < 4; ++am) {
#pragma unroll
            for (int bn = 0; bn < 4; ++bn)
                acc[am][bn] = __builtin_amdgcn_mfma_f32_16x16x32_bf16(af[am], bfv[bn], acc[am][bn], 0, 0, 0);
        }
    }

    // epilogue: bias + exact GELU in place, accumulate row stats
    float bc[4], gm[4], bt[4];
#pragma unroll
    for (int bn = 0; bn < 4; ++bn) {
        int col = wn * 64 + bn * 16 + r;
        bc[bn] = bias[col];
        gm[bn] = gamma[col];
        bt[bn] = beta[col];
    }
#pragma unroll
    for (int am = 0; am < 4; ++am) {
#pragma unroll
        for (int i = 0; i < 4; ++i) {
            float s = 0.f, ss = 0.f;
#pragma unroll
            for (int bn = 0; bn < 4; ++bn) {
                float v = acc[am][bn][i] + bc[bn];
                v = 0.5f * v * (1.f + erff(v * 0.70710678118654752f));
                acc[am][bn][i] = v;
                s += v;
                ss += v * v;
            }
#pragma unroll
            for (int msk = 1; msk < 16; msk <<= 1) {
                s += __shfl_xor(s, msk);
                ss += __shfl_xor(ss, msk);
            }
            if (r == 0) {
                int row = am * 16 + q * 4 + i;
                rs[row][wn] = s;
                rss[row][wn] = ss;
            }
        }
    }
    __syncthreads();
#pragma unroll
    for (int am = 0; am < 4; ++am) {
#pragma unroll
        for (int i = 0; i < 4; ++i) {
            int row = am * 16 + q * 4 + i;
            float s = rs[row][0] + rs[row][1] + rs[row][2] + rs[row][3];
            float ss = rss[row][0] + rss[row][1] + rss[row][2] + rss[row][3];
            float mu = s * (1.f / HID);
            float var = ss * (1.f / HID) - mu * mu;
            float inv = rsqrtf(var + 1e-5f);
#pragma unroll
            for (int bn = 0; bn < 4; ++bn) {
                int col = wn * 64 + bn * 16 + r;
                outp[(size_t)(m0 + row) * HID + col] = (acc[am][bn][i] - mu) * inv * gm[bn] + bt[bn];
            }
        }
    }
}

// ---------------------------------------------------------------- launch
extern "C" void kernel_launch(void* const* d_in, const int* in_sizes, int n_in,
                              void* d_out, int out_size, void* d_ws, size_t ws_size,
                              hipStream_t stream) {
    const float* P     = (const float*)d_in[0];
    const float* S     = (const float*)d_in[1];
    const void*  E     = d_in[2];
    const float* W     = (const float*)d_in[3];
    const float* bias  = (const float*)d_in[4];
    const float* gamma = (const float*)d_in[5];
    const float* beta  = (const float*)d_in[6];

    float* out = (float*)d_out;            // seg_low [40000*256]
    float* raw = out + (size_t)NSEG * HID; // seg_low_raw [40000*256]

    char* ws = (char*)d_ws;
    size_t off = 0;
    auto alloc = [&](size_t bytes) -> void* {
        void* p = ws + off;
        off += (bytes + 255) & ~(size_t)255;
        return p;
    };
    unsigned short* xcat   = (unsigned short*)alloc((size_t)NSEG * KCAT * 2);
    unsigned short* Pt     = (unsigned short*)alloc((size_t)HID * NREG * 2);
    unsigned short* Wt     = (unsigned short*)alloc((size_t)HID * KCAT * 2);
    int*            deg    = (int*)alloc((size_t)NSEG * 4);
    float*          dinv   = (float*)alloc((size_t)NSEG * 4);
    int*            cnt    = (int*)alloc((size_t)NSEG * 4);
    int*            rowptr = (int*)alloc((size_t)(NSEG + 1) * 4);
    int*            cursor = (int*)alloc((size_t)NSEG * 4);
    int*            colidx = (int*)alloc((size_t)NEDGE * 4);
    float*          val    = (float*)alloc((size_t)NEDGE * 4);
    int*            bsum   = (int*)alloc((size_t)NBLK * 4);
    int*            boff   = (int*)alloc((size_t)NBLK * 4);
    int*            flag   = (int*)alloc(256);
    if (off > ws_size) return;

    hipMemsetAsync(deg, 0, (size_t)NSEG * 4, stream);
    hipMemsetAsync(cnt, 0, (size_t)NSEG * 4, stream);

    detect_kernel<<<1, 64, 0, stream>>>((const unsigned int*)E, flag);
    prep_pt_kernel<<<HID, 256, 0, stream>>>(P, Pt);
    prep_wt_kernel<<<HID, 256, 0, stream>>>(W, Wt);

    deg_cnt_kernel<<<NEDGE / 256, 256, 0, stream>>>(E, flag, deg, cnt);
    dinv_kernel<<<(NSEG + 255) / 256, 256, 0, stream>>>(deg, dinv);
    scan1_kernel<<<NBLK, 256, 0, stream>>>(cnt, bsum);
    scan2_kernel<<<1, 256, 0, stream>>>(bsum, boff, rowptr);
    scan3_kernel<<<NBLK, 256, 0, stream>>>(cnt, boff, rowptr, cursor);
    scatter_kernel<<<NEDGE / 256, 256, 0, stream>>>(E, flag, dinv, cursor, colidx, val);

    gemm1_kernel<<<NSEG / 64, 256, 0, stream>>>(S, Pt, raw, xcat);

    prop_kernel<<<NSEG / 4, 256, 0, stream>>>(xcat, rowptr, colidx, val, 0 * HID, 1 * HID, -1, 1.f);
    prop_kernel<<<NSEG / 4, 256, 0, stream>>>(xcat, rowptr, colidx, val, 1 * HID, 2 * HID, 0 * HID, 2.f);
    prop_kernel<<<NSEG / 4, 256, 0, stream>>>(xcat, rowptr, colidx, val, 2 * HID, 3 * HID, 1 * HID, 2.f);
    prop_kernel<<<NSEG / 4, 256, 0, stream>>>(xcat, rowptr, colidx, val, 3 * HID, 4 * HID, 2 * HID, 2.f);

    gemm2_kernel<<<NSEG / 64, 256, 0, stream>>>(xcat, Wt, bias, gamma, beta, out);
}

// Round 4
// 445.147 us; speedup vs baseline: 1.5853x; 1.0552x over previous
//
#include <hip/hip_runtime.h>

#define NSEG 40000
#define NREG 1000
#define NEDGE 640000
#define HID 256
#define KCAT 1280   // 5 * HID
#define KP1 1024    // padded K for gemm1 (Pt zero-padded cols 1000..1023)
#define NBLK 157    // ceil(NSEG/256)

typedef float f32x4 __attribute__((ext_vector_type(4)));
typedef short s16x8 __attribute__((ext_vector_type(8)));
typedef unsigned short u16x4 __attribute__((ext_vector_type(4)));
typedef unsigned short u16x8 __attribute__((ext_vector_type(8)));

typedef __attribute__((address_space(3))) unsigned int lds_u32;
typedef __attribute__((address_space(1))) const unsigned int glb_u32;

__device__ __forceinline__ void dma16(const void* g, void* l) {
    // wave-uniform LDS base; HW writes lane i's 16B at base + i*16.
    __builtin_amdgcn_global_load_lds((glb_u32*)g, (lds_u32*)l, 16, 0, 0);
}

__device__ __forceinline__ unsigned short f2bf(float f) {
    unsigned u = __builtin_bit_cast(unsigned, f);
    u += 0x7FFFu + ((u >> 16) & 1u);   // round-to-nearest-even
    return (unsigned short)(u >> 16);
}
__device__ __forceinline__ float bf2f(unsigned short h) {
    unsigned u = ((unsigned)h) << 16;
    return __builtin_bit_cast(float, u);
}

__device__ __forceinline__ f32x4 mfma16(s16x8 a, s16x8 b, f32x4 c) {
    return __builtin_amdgcn_mfma_f32_16x16x32_bf16(a, b, c, 0, 0, 0);
}

// ---------------------------------------------------------------- edge dtype
__global__ void detect_kernel(const unsigned int* __restrict__ E, int* flag) {
    int lane = threadIdx.x;
    unsigned v = E[2 * lane + 1];
    unsigned long long m = __ballot(v == 0u);
    if (lane == 0) *flag = (__popcll(m) >= 48) ? 1 : 0;
}

__device__ __forceinline__ int edge_at(const void* E, int idx, int is64) {
    return is64 ? (int)((const long long*)E)[idx] : ((const int*)E)[idx];
}

// ---------------------------------------------------------------- CSR build
__global__ __launch_bounds__(256) void deg_cnt_kernel(const void* __restrict__ E,
                                                      const int* __restrict__ flag,
                                                      int* deg, int* cnt) {
    int e = blockIdx.x * 256 + threadIdx.x;
    if (e >= NEDGE) return;
    int is64 = *flag;
    int s = edge_at(E, e, is64);
    int d = edge_at(E, e + NEDGE, is64);
    if (s != d) {
        atomicAdd(&deg[s], 1);
        atomicAdd(&cnt[d], 1);
    }
}

__global__ __launch_bounds__(256) void dinv_kernel(const int* __restrict__ deg,
                                                   float* __restrict__ dinv) {
    int i = blockIdx.x * 256 + threadIdx.x;
    if (i < NSEG) {
        int d = deg[i];
        dinv[i] = d > 0 ? rsqrtf((float)d) : 0.f;
    }
}

// --- hierarchical scan
__global__ __launch_bounds__(256) void scan1_kernel(const int* __restrict__ cnt,
                                                    int* __restrict__ bsum) {
    __shared__ int sh[256];
    int t = threadIdx.x;
    int i = blockIdx.x * 256 + t;
    sh[t] = (i < NSEG) ? cnt[i] : 0;
    __syncthreads();
    for (int o = 128; o > 0; o >>= 1) {
        if (t < o) sh[t] += sh[t + o];
        __syncthreads();
    }
    if (t == 0) bsum[blockIdx.x] = sh[0];
}

__global__ __launch_bounds__(256) void scan2_kernel(const int* __restrict__ bsum,
                                                    int* __restrict__ boff,
                                                    int* __restrict__ rowptr) {
    __shared__ int sh[256];
    int t = threadIdx.x;
    int v = (t < NBLK) ? bsum[t] : 0;
    sh[t] = v;
    __syncthreads();
    for (int o = 1; o < 256; o <<= 1) {
        int x = 0;
        if (t >= o) x = sh[t - o];
        __syncthreads();
        if (t >= o) sh[t] += x;
        __syncthreads();
    }
    if (t < NBLK) boff[t] = sh[t] - v;
    if (t == 255) rowptr[NSEG] = sh[255];
}

__global__ __launch_bounds__(256) void scan3_kernel(const int* __restrict__ cnt,
                                                    const int* __restrict__ boff,
                                                    int* __restrict__ rowptr,
                                                    int* __restrict__ cursor) {
    __shared__ int sh[256];
    int t = threadIdx.x;
    int i = blockIdx.x * 256 + t;
    int v = (i < NSEG) ? cnt[i] : 0;
    sh[t] = v;
    __syncthreads();
    for (int o = 1; o < 256; o <<= 1) {
        int x = 0;
        if (t >= o) x = sh[t - o];
        __syncthreads();
        if (t >= o) sh[t] += x;
        __syncthreads();
    }
    if (i < NSEG) {
        int p = boff[blockIdx.x] + sh[t] - v;
        rowptr[i] = p;
        cursor[i] = p;
    }
}

__global__ __launch_bounds__(256) void scatter_kernel(const void* __restrict__ E,
                                                      const int* __restrict__ flag,
                                                      const float* __restrict__ dinv,
                                                      int* cursor,
                                                      int* __restrict__ colidx,
                                                      float* __restrict__ val) {
    int e = blockIdx.x * 256 + threadIdx.x;
    if (e >= NEDGE) return;
    int is64 = *flag;
    int s = edge_at(E, e, is64);
    int d = edge_at(E, e + NEDGE, is64);
    if (s != d) {
        int pos = atomicAdd(&cursor[d], 1);
        colidx[pos] = s;
        val[pos] = -dinv[s] * dinv[d];
    }
}

// ---------------------------------------------------------------- weight prep
// Pt[n][k] zero-padded to KP1 cols; Wt[n][k] (KCAT already /32).
__global__ void prep_pt_kernel(const float* __restrict__ P, unsigned short* __restrict__ Pt) {
    int n = blockIdx.x;
    for (int k = threadIdx.x; k < KP1; k += blockDim.x)
        Pt[(size_t)n * KP1 + k] = (k < NREG) ? f2bf(P[(size_t)k * HID + n]) : (unsigned short)0;
}
__global__ void prep_wt_kernel(const float* __restrict__ W, unsigned short* __restrict__ Wt) {
    int n = blockIdx.x;
    for (int k = threadIdx.x; k < KCAT; k += blockDim.x)
        Wt[(size_t)n * KCAT + k] = f2bf(W[(size_t)k * HID + n]);
}

// ---------------------------------------------------------------- GEMM1
// raw = S @ P ; bf16 copy into Xcat seg 0.
// 512 thr = 8 waves (2 M x 4 N), BM=64 BN=256 BK=32, double-buffered.
// B: global_load_lds from padded Pt (granule-XOR pre-swizzled source).
// A: fp32 reg-stage -> bf16 -> padded LDS (80B rows: 2-way, free).
__global__ __launch_bounds__(512) void gemm1_kernel(const float* __restrict__ S,
                                                    const unsigned short* __restrict__ Pt,
                                                    float* __restrict__ raw,
                                                    unsigned short* __restrict__ xcat) {
    __shared__ unsigned short Af[2][64][40];
    __shared__ unsigned short Bs[2][256 * 32];
    const int tid = threadIdx.x;
    const int lane = tid & 63, wid = tid >> 6;
    const int wm = wid >> 2, wn = wid & 3;
    const int r = lane & 15, q = lane >> 4;
    const int qx = q ^ (r & 3);               // inverse of source granule swizzle
    const int m0 = blockIdx.x * 64;
    const int arow = tid >> 3, acol = (tid & 7) * 4;
    const int j0 = 2 * wid, j1 = j0 + 1;      // B dma chunks (1KB = 16 rows each)
    const int brow0 = j0 * 16 + (lane >> 2), brow1 = j1 * 16 + (lane >> 2);
    const int bcol = (((lane & 3) ^ ((lane >> 2) & 3)) << 3);  // pre-swizzled src granule

    f32x4 acc[2][4] = {};
    const float* aptr = S + (size_t)(m0 + arow) * NREG;

    auto stageB = [&](int c, int kb) {
        dma16(Pt + (size_t)brow0 * KP1 + kb + bcol, &Bs[c][j0 * 512]);
        dma16(Pt + (size_t)brow1 * KP1 + kb + bcol, &Bs[c][j1 * 512]);
    };
    auto loadA = [&](int kb) -> f32x4 {
        int k0 = kb + acol;
        if (k0 + 4 > NREG) k0 = 0;  // tail: garbage x B-pad-zeros = 0
        return *(const f32x4*)(aptr + k0);
    };
    auto writeA = [&](int c, f32x4 a) {
        u16x4 o = {f2bf(a[0]), f2bf(a[1]), f2bf(a[2]), f2bf(a[3])};
        *(u16x4*)&Af[c][arow][acol] = o;
    };

    stageB(0, 0);
    writeA(0, loadA(0));
    __syncthreads();   // drains DMA vmcnt too

    for (int t = 0; t < 32; ++t) {
        const int c = t & 1;
        f32x4 an;
        if (t < 31) {
            stageB(c ^ 1, (t + 1) * 32);
            an = loadA((t + 1) * 32);
        }
        s16x8 af[2], bf[4];
#pragma unroll
        for (int am = 0; am < 2; ++am)
            af[am] = *(const s16x8*)&Af[c][wm * 32 + am * 16 + r][q * 8];
#pragma unroll
        for (int bn = 0; bn < 4; ++bn)
            bf[bn] = *(const s16x8*)&Bs[c][(wn * 64 + bn * 16 + r) * 32 + qx * 8];
#pragma unroll
        for (int am = 0; am < 2; ++am)
#pragma unroll
            for (int bn = 0; bn < 4; ++bn)
                acc[am][bn] = mfma16(af[am], bf[bn], acc[am][bn]);
        if (t < 31) writeA(c ^ 1, an);
        __syncthreads();
    }

#pragma unroll
    for (int am = 0; am < 2; ++am) {
        int rowb = m0 + wm * 32 + am * 16 + q * 4;
#pragma unroll
        for (int bn = 0; bn < 4; ++bn) {
            int col = wn * 64 + bn * 16 + r;
#pragma unroll
            for (int i = 0; i < 4; ++i) {
                float v = acc[am][bn][i];
                raw[(size_t)(rowb + i) * HID + col] = v;
                xcat[(size_t)(rowb + i) * KCAT + col] = f2bf(v);
            }
        }
    }
}

// ---------------------------------------------------------------- propagation
__global__ __launch_bounds__(256) void prop_kernel(unsigned short* xcat,
                                                   const int* __restrict__ rowptr,
                                                   const int* __restrict__ colidx,
                                                   const float* __restrict__ val,
                                                   int inOff, int outOff, int subOff,
                                                   float scale) {
    int g = blockIdx.x * 4 + (threadIdx.x >> 6);
    int lane = threadIdx.x & 63;
    int e0 = rowptr[g], e1 = rowptr[g + 1];
    float a0 = 0.f, a1 = 0.f, a2 = 0.f, a3 = 0.f;
    const unsigned short* xin = xcat + inOff + lane * 4;
    for (int base = e0; base < e1; base += 64) {
        int m = e1 - base;
        if (m > 64) m = 64;
        int cc = 0;
        float vv = 0.f;
        if (lane < m) {
            cc = colidx[base + lane];
            vv = val[base + lane];
        }
        int i = 0;
        for (; i + 8 <= m; i += 8) {
            u16x4 t[8];
#pragma unroll
            for (int j = 0; j < 8; ++j) {
                int c = __shfl(cc, i + j);
                t[j] = *(const u16x4*)(xin + (size_t)c * KCAT);
            }
#pragma unroll
            for (int j = 0; j < 8; ++j) {
                float v = __shfl(vv, i + j);
                a0 += v * bf2f(t[j][0]);
                a1 += v * bf2f(t[j][1]);
                a2 += v * bf2f(t[j][2]);
                a3 += v * bf2f(t[j][3]);
            }
        }
        for (; i < m; ++i) {
            int c = __shfl(cc, i);
            float v = __shfl(vv, i);
            u16x4 t = *(const u16x4*)(xin + (size_t)c * KCAT);
            a0 += v * bf2f(t[0]);
            a1 += v * bf2f(t[1]);
            a2 += v * bf2f(t[2]);
            a3 += v * bf2f(t[3]);
        }
    }
    a0 *= scale; a1 *= scale; a2 *= scale; a3 *= scale;
    if (subOff >= 0) {
        u16x4 p = *(const u16x4*)(xcat + (size_t)g * KCAT + subOff + lane * 4);
        a0 -= bf2f(p[0]); a1 -= bf2f(p[1]); a2 -= bf2f(p[2]); a3 -= bf2f(p[3]);
    }
    u16x4 o = {f2bf(a0), f2bf(a1), f2bf(a2), f2bf(a3)};
    *(u16x4*)(xcat + (size_t)g * KCAT + outOff + lane * 4) = o;
}

// ---------------------------------------------------------------- GEMM2 + GELU + LN (fused)
// 512 thr, BM=64 BN=256 BK=32, dbuf, A and B both via global_load_lds.
__global__ __launch_bounds__(512) void gemm2_kernel(const unsigned short* __restrict__ xcat,
                                                    const unsigned short* __restrict__ Wt,
                                                    const float* __restrict__ bias,
                                                    const float* __restrict__ gamma,
                                                    const float* __restrict__ beta,
                                                    float* __restrict__ outp) {
    __shared__ unsigned short Af[2][64 * 32];
    __shared__ unsigned short Bs[2][256 * 32];
    __shared__ float rs[64][4];
    __shared__ float rss[64][4];
    const int tid = threadIdx.x;
    const int lane = tid & 63, wid = tid >> 6;
    const int wm = wid >> 2, wn = wid & 3;
    const int r = lane & 15, q = lane >> 4;
    const int qx = q ^ (r & 3);
    const int m0 = blockIdx.x * 64;
    const int j0 = 2 * wid, j1 = j0 + 1;
    const int brow0 = j0 * 16 + (lane >> 2), brow1 = j1 * 16 + (lane >> 2);
    const int arowd = wid * 16 + (lane >> 2);               // A dma (waves 0..3)
    const int bcol = (((lane & 3) ^ ((lane >> 2) & 3)) << 3);

    f32x4 acc[2][4] = {};

    auto stage = [&](int c, int kb) {
        dma16(Wt + (size_t)brow0 * KCAT + kb + bcol, &Bs[c][j0 * 512]);
        dma16(Wt + (size_t)brow1 * KCAT + kb + bcol, &Bs[c][j1 * 512]);
        if (wid < 4)
            dma16(xcat + (size_t)(m0 + arowd) * KCAT + kb + bcol, &Af[c][wid * 512]);
    };

    stage(0, 0);
    __syncthreads();

    for (int t = 0; t < 40; ++t) {
        const int c = t & 1;
        if (t < 39) stage(c ^ 1, (t + 1) * 32);
        s16x8 af[2], bf[4];
#pragma unroll
        for (int am = 0; am < 2; ++am)
            af[am] = *(const s16x8*)&Af[c][(wm * 32 + am * 16 + r) * 32 + qx * 8];
#pragma unroll
        for (int bn = 0; bn < 4; ++bn)
            bf[bn] = *(const s16x8*)&Bs[c][(wn * 64 + bn * 16 + r) * 32 + qx * 8];
#pragma unroll
        for (int am = 0; am < 2; ++am)
#pragma unroll
            for (int bn = 0; bn < 4; ++bn)
                acc[am][bn] = mfma16(af[am], bf[bn], acc[am][bn]);
        __syncthreads();
    }

    // epilogue: bias + exact GELU, row stats, LN, store
    float bc[4], gm[4], bt[4];
#pragma unroll
    for (int bn = 0; bn < 4; ++bn) {
        int col = wn * 64 + bn * 16 + r;
        bc[bn] = bias[col];
        gm[bn] = gamma[col];
        bt[bn] = beta[col];
    }
#pragma unroll
    for (int am = 0; am < 2; ++am) {
#pragma unroll
        for (int i = 0; i < 4; ++i) {
            float s = 0.f, ss = 0.f;
#pragma unroll
            for (int bn = 0; bn < 4; ++bn) {
                float v = acc[am][bn][i] + bc[bn];
                v = 0.5f * v * (1.f + erff(v * 0.70710678118654752f));
                acc[am][bn][i] = v;
                s += v;
                ss += v * v;
            }
#pragma unroll
            for (int msk = 1; msk < 16; msk <<= 1) {
                s += __shfl_xor(s, msk);
                ss += __shfl_xor(ss, msk);
            }
            if (r == 0) {
                int row = wm * 32 + am * 16 + q * 4 + i;
                rs[row][wn] = s;
                rss[row][wn] = ss;
            }
        }
    }
    __syncthreads();
#pragma unroll
    for (int am = 0; am < 2; ++am) {
#pragma unroll
        for (int i = 0; i < 4; ++i) {
            int row = wm * 32 + am * 16 + q * 4 + i;
            float s = rs[row][0] + rs[row][1] + rs[row][2] + rs[row][3];
            float ss = rss[row][0] + rss[row][1] + rss[row][2] + rss[row][3];
            float mu = s * (1.f / HID);
            float var = ss * (1.f / HID) - mu * mu;
            float inv = rsqrtf(var + 1e-5f);
#pragma unroll
            for (int bn = 0; bn < 4; ++bn) {
                int col = wn * 64 + bn * 16 + r;
                outp[(size_t)(m0 + row) * HID + col] = (acc[am][bn][i] - mu) * inv * gm[bn] + bt[bn];
            }
        }
    }
}

// ---------------------------------------------------------------- launch
extern "C" void kernel_launch(void* const* d_in, const int* in_sizes, int n_in,
                              void* d_out, int out_size, void* d_ws, size_t ws_size,
                              hipStream_t stream) {
    const float* P     = (const float*)d_in[0];
    const float* S     = (const float*)d_in[1];
    const void*  E     = d_in[2];
    const float* W     = (const float*)d_in[3];
    const float* bias  = (const float*)d_in[4];
    const float* gamma = (const float*)d_in[5];
    const float* beta  = (const float*)d_in[6];

    float* out = (float*)d_out;            // seg_low [40000*256]
    float* raw = out + (size_t)NSEG * HID; // seg_low_raw [40000*256]

    char* ws = (char*)d_ws;
    size_t off = 0;
    auto alloc = [&](size_t bytes) -> void* {
        void* p = ws + off;
        off += (bytes + 255) & ~(size_t)255;
        return p;
    };
    unsigned short* xcat   = (unsigned short*)alloc((size_t)NSEG * KCAT * 2);
    unsigned short* Pt     = (unsigned short*)alloc((size_t)HID * KP1 * 2);
    unsigned short* Wt     = (unsigned short*)alloc((size_t)HID * KCAT * 2);
    int*            deg    = (int*)alloc((size_t)NSEG * 4);
    float*          dinv   = (float*)alloc((size_t)NSEG * 4);
    int*            cnt    = (int*)alloc((size_t)NSEG * 4);
    int*            rowptr = (int*)alloc((size_t)(NSEG + 1) * 4);
    int*            cursor = (int*)alloc((size_t)NSEG * 4);
    int*            colidx = (int*)alloc((size_t)NEDGE * 4);
    float*          val    = (float*)alloc((size_t)NEDGE * 4);
    int*            bsum   = (int*)alloc((size_t)NBLK * 4);
    int*            boff   = (int*)alloc((size_t)NBLK * 4);
    int*            flag   = (int*)alloc(256);
    if (off > ws_size) return;

    hipMemsetAsync(deg, 0, (size_t)NSEG * 4, stream);
    hipMemsetAsync(cnt, 0, (size_t)NSEG * 4, stream);

    detect_kernel<<<1, 64, 0, stream>>>((const unsigned int*)E, flag);
    prep_pt_kernel<<<HID, 256, 0, stream>>>(P, Pt);
    prep_wt_kernel<<<HID, 256, 0, stream>>>(W, Wt);

    deg_cnt_kernel<<<NEDGE / 256, 256, 0, stream>>>(E, flag, deg, cnt);
    dinv_kernel<<<(NSEG + 255) / 256, 256, 0, stream>>>(deg, dinv);
    scan1_kernel<<<NBLK, 256, 0, stream>>>(cnt, bsum);
    scan2_kernel<<<1, 256, 0, stream>>>(bsum, boff, rowptr);
    scan3_kernel<<<NBLK, 256, 0, stream>>>(cnt, boff, rowptr, cursor);
    scatter_kernel<<<NEDGE / 256, 256, 0, stream>>>(E, flag, dinv, cursor, colidx, val);

    gemm1_kernel<<<NSEG / 64, 512, 0, stream>>>(S, Pt, raw, xcat);

    prop_kernel<<<NSEG / 4, 256, 0, stream>>>(xcat, rowptr, colidx, val, 0 * HID, 1 * HID, -1, 1.f);
    prop_kernel<<<NSEG / 4, 256, 0, stream>>>(xcat, rowptr, colidx, val, 1 * HID, 2 * HID, 0 * HID, 2.f);
    prop_kernel<<<NSEG / 4, 256, 0, stream>>>(xcat, rowptr, colidx, val, 2 * HID, 3 * HID, 1 * HID, 2.f);
    prop_kernel<<<NSEG / 4, 256, 0, stream>>>(xcat, rowptr, colidx, val, 3 * HID, 4 * HID, 2 * HID, 2.f);

    gemm2_kernel<<<NSEG / 64, 512, 0, stream>>>(xcat, Wt, bias, gamma, beta, out);
}